// Round 20
// baseline (93.099 us; speedup 1.0000x reference)
//
#include <hip/hip_runtime.h>
#include <math.h>

// CARE position encoding, Cl(5,0,0), MV=32.
// Round 20: round-19 confirmed scratch fix (kernel ~15us vs 10.4us floor).
// Residue = scalar LDS traffic (PAD=33 rows unaligned -> 128x ds_*_b32/thread).
// Fix: XOR-swizzled v4f LDS blocks: lds4[row*8 + (b ^ (row&7))] -> all LDS ops
// ds_read/write_b128 (32 ops/thread), banks uniformly loaded, 32KB -> 5 blk/CU.

#define MV 32
#define NB 10
#define NR 11
#define TILE 256

typedef float v4f  __attribute__((ext_vector_type(4)));
typedef float v16f __attribute__((ext_vector_type(16)));
typedef float v32f __attribute__((ext_vector_type(32)));

__host__ __device__ constexpr int popc_c(unsigned v) {
    int c = 0;
    while (v) { c += (int)(v & 1u); v >>= 1; }
    return c;
}
__host__ __device__ constexpr float csign(int a, int b) {
    int s = 0;
    unsigned aa = ((unsigned)a) >> 1;
    while (aa) { s += popc_c(aa & (unsigned)b); aa >>= 1; }
    return (s & 1) ? -1.0f : 1.0f;
}

__device__ constexpr int BIVc[NB]  = {3, 5, 6, 9, 10, 12, 17, 18, 20, 24};
__device__ constexpr int RIDXc[NR] = {0, 3, 5, 6, 9, 10, 12, 17, 18, 20, 24};

// ---- bf + theta^2 (constexpr blade index; every bivector squares to -1) ----
template<int T>
__device__ __forceinline__ void mk_bf(const float* __restrict__ Bx,
                                      const float* __restrict__ By,
                                      float thx, float thy, v16f& bf, float& ts) {
    constexpr int i = BIVc[T];
    float v = 0.5f * (thx * Bx[i] + thy * By[i]);
    bf[T] = v;
    ts = fmaf(v, v, ts);
    if constexpr (T + 1 < NB) mk_bf<T + 1>(Bx, By, thx, thy, bf, ts);
}

template<int T>
__device__ __forceinline__ void mk_rot(float sinc, const v16f& bf, v16f& r) {
    r[T + 1] = sinc * bf[T];
    if constexpr (T + 1 < NB) mk_rot<T + 1>(sinc, bf, r);
}

// ---- LDS v4f blocks <-> v32f registers (swizzled, b128 traffic) ----
template<int B>
__device__ __forceinline__ void ldxv(const v4f* __restrict__ l4, int tid, v32f& xv) {
    v4f q = l4[tid * 8 + (B ^ (tid & 7))];
    xv[4 * B + 0] = q.x; xv[4 * B + 1] = q.y;
    xv[4 * B + 2] = q.z; xv[4 * B + 3] = q.w;
    if constexpr (B + 1 < 8) ldxv<B + 1>(l4, tid, xv);
}
template<int B>
__device__ __forceinline__ void stres(v4f* __restrict__ l4, int tid, const v32f& o) {
    v4f q;
    q.x = o[4 * B + 0]; q.y = o[4 * B + 1];
    q.z = o[4 * B + 2]; q.w = o[4 * B + 3];
    l4[tid * 8 + (B ^ (tid & 7))] = q;
    if constexpr (B + 1 < 8) stres<B + 1>(l4, tid, o);
}

// ---- stage 1: rx[L] = sum_t csign(i, i^L) * r[t] * xv[i^L] ----
template<int L, int T>
__device__ __forceinline__ float s1t(const v32f& xv, const v16f& r, float acc) {
    constexpr int i = RIDXc[T];
    constexpr int j = i ^ L;
    constexpr float sg = csign(i, j);
    acc = fmaf(sg > 0.f ? r[T] : -r[T], xv[j], acc);
    if constexpr (T + 1 < NR) return s1t<L, T + 1>(xv, r, acc);
    else return acc;
}
template<int L>
__device__ __forceinline__ void s1(const v32f& xv, const v16f& r, v32f& rx) {
    rx[L] = s1t<L, 0>(xv, r, 0.f);
    if constexpr (L + 1 < MV) s1<L + 1>(xv, r, rx);
}

// ---- stage 2: o[L] = sum_t csign(L^m, m)*(t==0?+1:-1) * r[t] * rx[L^m] ----
template<int L, int T>
__device__ __forceinline__ float s2t(const v32f& rx, const v16f& r, float acc) {
    constexpr int m = RIDXc[T];
    constexpr int j = L ^ m;
    constexpr float sg = csign(j, m) * (T == 0 ? 1.f : -1.f);
    acc = fmaf(sg > 0.f ? r[T] : -r[T], rx[j], acc);
    if constexpr (T + 1 < NR) return s2t<L, T + 1>(rx, r, acc);
    else return acc;
}
template<int L>
__device__ __forceinline__ void s2(const v32f& rx, const v16f& r, v32f& o) {
    o[L] = s2t<L, 0>(rx, r, 0.f);
    if constexpr (L + 1 < MV) s2<L + 1>(rx, r, o);
}

__global__ __launch_bounds__(256) void care_kernel(
    const float* __restrict__ x,
    const int*   __restrict__ pos,
    const float* __restrict__ Bx,
    const float* __restrict__ By,
    float*       __restrict__ out,
    int n_pos)
{
    __shared__ v4f lds4[TILE * 8];     // [row][8 x v4f], col XOR-swizzled by row&7
    const int tid  = threadIdx.x;
    const int base = blockIdx.x * TILE;

    // ---- phase 1: coalesced global -> LDS (b128 writes, swizzled) ----
    const v4f* xg = reinterpret_cast<const v4f*>(x + (size_t)base * MV);
#pragma unroll
    for (int k = 0; k < 8; k++) {
        const int idx = k * 256 + tid;
        const int row = idx >> 3;
        const int b   = idx & 7;
        lds4[row * 8 + (b ^ (row & 7))] = xg[idx];
    }

    // ---- rotor (pure registers, inline hw trig; overlaps load latency) ----
    const int p = base + tid;
    int pp = pos[p];
    pp = pp < 0 ? 0 : (pp > 8191 ? 8191 : pp);
    const float posf = (float)pp;
    const float thx = posf;            // freqs[0] = 1.0
    const float thy = posf * 0.01f;    // freqs[1] = 0.01

    v16f bf;
    float theta_sq = 0.f;
    mk_bf<0>(Bx, By, thx, thy, bf, theta_sq);

    const float theta = sqrtf(theta_sq + 1e-16f);
    const bool  is_small = theta_sq < 1e-10f;
    const float theta_safe = theta + ((theta < 1e-10f) ? 1e-10f : 0.f);

    float rev = theta_safe * 0.15915494309189535f;   // theta / 2pi
    rev -= floorf(rev);
#if __has_builtin(__builtin_amdgcn_sinf) && __has_builtin(__builtin_amdgcn_cosf)
    const float s = __builtin_amdgcn_sinf(rev);
    const float c = __builtin_amdgcn_cosf(rev);
#else
    const float ang = rev * 6.283185307179586f;
    const float s = sinf(ang);
    const float c = cosf(ang);
#endif
    const float sinc = is_small ? 1.f : (s / theta_safe);
    const float cosv = is_small ? 1.f : c;

    v16f r;
    r[0] = cosv;
    mk_rot<0>(sinc, bf, r);

    __syncthreads();

    // ---- own row: LDS -> regs (b128), gp twice, regs -> LDS (b128) ----
    v32f xv;
    ldxv<0>(lds4, tid, xv);

    v32f rx, o;
    s1<0>(xv, r, rx);
    s2<0>(rx, r, o);
    stres<0>(lds4, tid, o);

    __syncthreads();

    // ---- phase 2: LDS -> coalesced global stores (b128 reads, swizzled) ----
    v4f* og = reinterpret_cast<v4f*>(out + (size_t)base * MV);
#pragma unroll
    for (int k = 0; k < 8; k++) {
        const int idx = k * 256 + tid;
        const int row = idx >> 3;
        const int b   = idx & 7;
        og[idx] = lds4[row * 8 + (b ^ (row & 7))];
    }
}

extern "C" void kernel_launch(void* const* d_in, const int* in_sizes, int n_in,
                              void* d_out, int out_size, void* d_ws, size_t ws_size,
                              hipStream_t stream) {
    const float* x   = (const float*)d_in[0];
    const int*   pos = (const int*)  d_in[1];
    const float* Bx  = (const float*)d_in[2];
    const float* By  = (const float*)d_in[3];
    float* out = (float*)d_out;

    int n_pos = in_sizes[0] / MV;  // 262144 positions
    int grid = (n_pos + TILE - 1) / TILE;
    care_kernel<<<grid, TILE, 0, stream>>>(x, pos, Bx, By, out, n_pos);
}